// Round 1
// baseline (1849.574 us; speedup 1.0000x reference)
//
#include <hip/hip_runtime.h>
#include <math.h>

#define B_  2
#define S_  2048
#define D_  1024
#define H_  16
#define HD_ 64
#define BS_ (B_ * S_)   // 4096 rows

// ---------------------------------------------------------------------------
// LayerNorm: one block (256 threads) per row of 1024 floats.
// ---------------------------------------------------------------------------
__global__ __launch_bounds__(256) void ln_kernel(const float* __restrict__ x,
                                                 const float* __restrict__ gamma,
                                                 const float* __restrict__ beta,
                                                 float* __restrict__ y)
{
    int row = blockIdx.x;
    float4 v = ((const float4*)(x + (size_t)row * D_))[threadIdx.x];
    float sum = v.x + v.y + v.z + v.w;
    float sq  = v.x * v.x + v.y * v.y + v.z * v.z + v.w * v.w;
#pragma unroll
    for (int off = 32; off > 0; off >>= 1) {
        sum += __shfl_down(sum, off);
        sq  += __shfl_down(sq, off);
    }
    __shared__ float s_sum[4], s_sq[4];
    int wave = threadIdx.x >> 6;
    if ((threadIdx.x & 63) == 0) { s_sum[wave] = sum; s_sq[wave] = sq; }
    __syncthreads();
    float tsum = s_sum[0] + s_sum[1] + s_sum[2] + s_sum[3];
    float tsq  = s_sq[0] + s_sq[1] + s_sq[2] + s_sq[3];
    float mean = tsum * (1.0f / D_);
    float var  = tsq * (1.0f / D_) - mean * mean;
    float rstd = rsqrtf(var + 1e-5f);
    float4 g = ((const float4*)gamma)[threadIdx.x];
    float4 b = ((const float4*)beta)[threadIdx.x];
    float4 o;
    o.x = (v.x - mean) * rstd * g.x + b.x;
    o.y = (v.y - mean) * rstd * g.y + b.y;
    o.z = (v.z - mean) * rstd * g.z + b.z;
    o.w = (v.w - mean) * rstd * g.w + b.w;
    ((float4*)(y + (size_t)row * D_))[threadIdx.x] = o;
}

// ---------------------------------------------------------------------------
// C[M][N] = A[M][K] * Bw[N][K]^T + bias[N]   (both row-major, K-contiguous)
// 64x64 tile, BK=16, 256 threads, 4x4 micro-tile per thread.
// ---------------------------------------------------------------------------
#define BM 64
#define BN 64
#define BK 16

__global__ __launch_bounds__(256) void gemm_nt(const float* __restrict__ A,
                                               const float* __restrict__ Bw,
                                               const float* __restrict__ bias,
                                               float* __restrict__ C,
                                               int M, int N, int K)
{
    __shared__ float As[BK][BM + 4];   // stride 68 floats: float4-aligned rows
    __shared__ float Bs[BK][BN + 4];
    int bm  = blockIdx.y * BM;
    int bn  = blockIdx.x * BN;
    int tid = threadIdx.x;
    int tx = tid & 15, ty = tid >> 4;
    int lr = tid >> 2;          // load row 0..63
    int lk = (tid & 3) << 2;    // load k-offset 0,4,8,12

    float acc[4][4] = {{0.f}};

    for (int k0 = 0; k0 < K; k0 += BK) {
        float4 av = *(const float4*)(A  + (size_t)(bm + lr) * K + k0 + lk);
        float4 bv = *(const float4*)(Bw + (size_t)(bn + lr) * K + k0 + lk);
        __syncthreads();
        As[lk + 0][lr] = av.x; As[lk + 1][lr] = av.y;
        As[lk + 2][lr] = av.z; As[lk + 3][lr] = av.w;
        Bs[lk + 0][lr] = bv.x; Bs[lk + 1][lr] = bv.y;
        Bs[lk + 2][lr] = bv.z; Bs[lk + 3][lr] = bv.w;
        __syncthreads();
#pragma unroll
        for (int kk = 0; kk < BK; kk++) {
            float4 a = *(const float4*)&As[kk][ty * 4];
            float4 b = *(const float4*)&Bs[kk][tx * 4];
            acc[0][0] += a.x * b.x; acc[0][1] += a.x * b.y; acc[0][2] += a.x * b.z; acc[0][3] += a.x * b.w;
            acc[1][0] += a.y * b.x; acc[1][1] += a.y * b.y; acc[1][2] += a.y * b.z; acc[1][3] += a.y * b.w;
            acc[2][0] += a.z * b.x; acc[2][1] += a.z * b.y; acc[2][2] += a.z * b.z; acc[2][3] += a.z * b.w;
            acc[3][0] += a.w * b.x; acc[3][1] += a.w * b.y; acc[3][2] += a.w * b.z; acc[3][3] += a.w * b.w;
        }
    }

    float4 bb = *(const float4*)(bias + bn + tx * 4);
#pragma unroll
    for (int i = 0; i < 4; i++) {
        int row = bm + ty * 4 + i;
        float4 o;
        o.x = acc[i][0] + bb.x;
        o.y = acc[i][1] + bb.y;
        o.z = acc[i][2] + bb.z;
        o.w = acc[i][3] + bb.w;
        *(float4*)(C + (size_t)row * N + bn + tx * 4) = o;
    }
}

// ---------------------------------------------------------------------------
// RoPE applied in place to q and k inside the qkv buffer.
// qkv layout per row: (H, 3, HD) -> offset h*192 + t*64 + hd.
// One thread handles the pair (hd=i, hd=i+32) of q and k, i in [0,32).
// ---------------------------------------------------------------------------
__global__ __launch_bounds__(256) void rope_kernel(float* __restrict__ qkv)
{
    int idx = blockIdx.x * blockDim.x + threadIdx.x;
    if (idx >= BS_ * H_ * 32) return;
    int i  = idx & 31;
    int h  = (idx >> 5) & 15;
    int bs = idx >> 9;
    int s  = bs & (S_ - 1);

    float inv_freq = powf(10000.0f, -(float)i / 32.0f);
    float ang = (float)s * inv_freq;
    float sn, cs;
    sincosf(ang, &sn, &cs);

    size_t base = (size_t)bs * (3 * D_) + h * (3 * HD_);
    float q1 = qkv[base + i],      q2 = qkv[base + 32 + i];
    qkv[base + i]      = q1 * cs - q2 * sn;
    qkv[base + 32 + i] = q2 * cs + q1 * sn;
    float k1 = qkv[base + 64 + i], k2 = qkv[base + 96 + i];
    qkv[base + 64 + i] = k1 * cs - k2 * sn;
    qkv[base + 96 + i] = k2 * cs + k1 * sn;
}

// ---------------------------------------------------------------------------
// Flash-style causal attention. Block = (q-tile of 64 rows, head, batch).
// 256 threads: thread (r = tid>>2, c = tid&3); thread owns 16 score cols and
// 16 output dims of its row. Online softmax state replicated across the 4
// lanes of each row group (wave-contiguous -> shuffle reductions).
// ---------------------------------------------------------------------------
__global__ __launch_bounds__(256) void attn_kernel(const float* __restrict__ qkv,
                                                   float* __restrict__ ctx)
{
    const int qt = blockIdx.x;   // 0..31
    const int h  = blockIdx.y;   // 0..15
    const int b  = blockIdx.z;   // 0..1
    const int tid = threadIdx.x;
    const int r = tid >> 2;      // 0..63
    const int c = tid & 3;       // 0..3

    __shared__ float Qs[64][68];
    __shared__ float Ks[64][68];
    __shared__ float Vs[64][68];
    __shared__ float Ps[64][68];

    const size_t row_stride = 3 * D_;  // 3072
    const float* qbase = qkv + ((size_t)(b * S_ + qt * 64)) * row_stride + h * (3 * HD_);

    for (int e = tid; e < 64 * 16; e += 256) {
        int row = e >> 4;
        int c4  = (e & 15) << 2;
        float4 v = *(const float4*)(qbase + (size_t)row * row_stride + c4);
        float4 sv; sv.x = v.x * 0.125f; sv.y = v.y * 0.125f; sv.z = v.z * 0.125f; sv.w = v.w * 0.125f;
        *(float4*)&Qs[row][c4] = sv;
    }

    float m_i = -INFINITY, l_i = 0.0f;
    float4 acc[4];
#pragma unroll
    for (int q4 = 0; q4 < 4; q4++) acc[q4] = make_float4(0.f, 0.f, 0.f, 0.f);

    const int qg = qt * 64 + r;

    for (int kt = 0; kt <= qt; kt++) {
        __syncthreads();   // previous iteration's PV done; Qs visible (iter 0)
        const float* kbase = qkv + ((size_t)(b * S_ + kt * 64)) * row_stride + h * (3 * HD_) + HD_;
        const float* vbase = kbase + HD_;
        for (int e = tid; e < 64 * 16; e += 256) {
            int row = e >> 4;
            int c4  = (e & 15) << 2;
            *(float4*)&Ks[row][c4] = *(const float4*)(kbase + (size_t)row * row_stride + c4);
            *(float4*)&Vs[row][c4] = *(const float4*)(vbase + (size_t)row * row_stride + c4);
        }
        __syncthreads();

        float sc[16];
#pragma unroll
        for (int j = 0; j < 16; j++) sc[j] = 0.0f;
        for (int hd0 = 0; hd0 < 64; hd0 += 4) {
            float4 qv = *(const float4*)&Qs[r][hd0];
#pragma unroll
            for (int j = 0; j < 16; j++) {
                float4 kv = *(const float4*)&Ks[c * 16 + j][hd0];
                sc[j] += qv.x * kv.x + qv.y * kv.y + qv.z * kv.z + qv.w * kv.w;
            }
        }

        if (kt == qt) {
#pragma unroll
            for (int j = 0; j < 16; j++) {
                int kg = kt * 64 + c * 16 + j;
                if (kg > qg) sc[j] = -INFINITY;
            }
        }

        float mt = sc[0];
#pragma unroll
        for (int j = 1; j < 16; j++) mt = fmaxf(mt, sc[j]);
        mt = fmaxf(mt, __shfl_xor(mt, 1));
        mt = fmaxf(mt, __shfl_xor(mt, 2));
        float m_new = fmaxf(m_i, mt);

        float p[16];
        float ps = 0.0f;
#pragma unroll
        for (int j = 0; j < 16; j++) { p[j] = __expf(sc[j] - m_new); ps += p[j]; }
        ps += __shfl_xor(ps, 1);
        ps += __shfl_xor(ps, 2);

        float alpha = __expf(m_i - m_new);
        l_i = l_i * alpha + ps;
        m_i = m_new;
#pragma unroll
        for (int q4 = 0; q4 < 4; q4++) {
            acc[q4].x *= alpha; acc[q4].y *= alpha; acc[q4].z *= alpha; acc[q4].w *= alpha;
        }

#pragma unroll
        for (int j = 0; j < 16; j++) Ps[r][c * 16 + j] = p[j];
        __syncthreads();

        for (int col = 0; col < 64; col++) {
            float pv = Ps[r][col];
#pragma unroll
            for (int q4 = 0; q4 < 4; q4++) {
                float4 vv = *(const float4*)&Vs[col][c * 16 + q4 * 4];
                acc[q4].x += pv * vv.x; acc[q4].y += pv * vv.y;
                acc[q4].z += pv * vv.z; acc[q4].w += pv * vv.w;
            }
        }
    }

    float inv_l = 1.0f / l_i;
    float* obase = ctx + ((size_t)(b * S_ + qg)) * D_ + h * HD_ + c * 16;
#pragma unroll
    for (int q4 = 0; q4 < 4; q4++) {
        float4 o;
        o.x = acc[q4].x * inv_l; o.y = acc[q4].y * inv_l;
        o.z = acc[q4].z * inv_l; o.w = acc[q4].w * inv_l;
        *(float4*)(obase + q4 * 4) = o;
    }
}

// ---------------------------------------------------------------------------
extern "C" void kernel_launch(void* const* d_in, const int* in_sizes, int n_in,
                              void* d_out, int out_size, void* d_ws, size_t ws_size,
                              hipStream_t stream)
{
    const float* hidden = (const float*)d_in[0];
    const float* gamma  = (const float*)d_in[1];
    const float* beta   = (const float*)d_in[2];
    const float* qkv_w  = (const float*)d_in[3];
    const float* qkv_b  = (const float*)d_in[4];
    const float* proj_w = (const float*)d_in[5];
    const float* proj_b = (const float*)d_in[6];
    float* out = (float*)d_out;

    char* ws = (char*)d_ws;
    float* x_ln = (float*)ws;                                   // 16 MB
    float* qkv  = (float*)(ws + (size_t)16 * 1024 * 1024);      // 48 MB
    float* ctx  = (float*)(ws + (size_t)64 * 1024 * 1024);      // 16 MB

    ln_kernel<<<BS_, 256, 0, stream>>>(hidden, gamma, beta, x_ln);

    gemm_nt<<<dim3((3 * D_) / BN, BS_ / BM), 256, 0, stream>>>(
        x_ln, qkv_w, qkv_b, qkv, BS_, 3 * D_, D_);

    rope_kernel<<<(BS_ * H_ * 32 + 255) / 256, 256, 0, stream>>>(qkv);

    attn_kernel<<<dim3(S_ / 64, H_, B_), 256, 0, stream>>>(qkv, ctx);

    gemm_nt<<<dim3(D_ / BN, BS_ / BM), 256, 0, stream>>>(
        ctx, proj_w, proj_b, out, BS_, D_, D_);
}

// Round 2
// 473.721 us; speedup vs baseline: 3.9044x; 3.9044x over previous
//
#include <hip/hip_runtime.h>
#include <math.h>

#define B_  2
#define S_  2048
#define D_  1024
#define H_  16
#define HD_ 64
#define BS_ (B_ * S_)   // 4096 rows

typedef __bf16 bf16_t;
typedef __bf16 bf16x8 __attribute__((ext_vector_type(8)));
typedef float  f32x4  __attribute__((ext_vector_type(4)));

// ---------------------------------------------------------------------------
// LayerNorm: one block (256 threads) per row of 1024 floats.
// ---------------------------------------------------------------------------
__global__ __launch_bounds__(256) void ln_kernel(const float* __restrict__ x,
                                                 const float* __restrict__ gamma,
                                                 const float* __restrict__ beta,
                                                 float* __restrict__ y)
{
    int row = blockIdx.x;
    float4 v = ((const float4*)(x + (size_t)row * D_))[threadIdx.x];
    float sum = v.x + v.y + v.z + v.w;
    float sq  = v.x * v.x + v.y * v.y + v.z * v.z + v.w * v.w;
#pragma unroll
    for (int off = 32; off > 0; off >>= 1) {
        sum += __shfl_down(sum, off);
        sq  += __shfl_down(sq, off);
    }
    __shared__ float s_sum[4], s_sq[4];
    int wave = threadIdx.x >> 6;
    if ((threadIdx.x & 63) == 0) { s_sum[wave] = sum; s_sq[wave] = sq; }
    __syncthreads();
    float tsum = s_sum[0] + s_sum[1] + s_sum[2] + s_sum[3];
    float tsq  = s_sq[0] + s_sq[1] + s_sq[2] + s_sq[3];
    float mean = tsum * (1.0f / D_);
    float var  = tsq * (1.0f / D_) - mean * mean;
    float rstd = rsqrtf(var + 1e-5f);
    float4 g = ((const float4*)gamma)[threadIdx.x];
    float4 b = ((const float4*)beta)[threadIdx.x];
    float4 o;
    o.x = (v.x - mean) * rstd * g.x + b.x;
    o.y = (v.y - mean) * rstd * g.y + b.y;
    o.z = (v.z - mean) * rstd * g.z + b.z;
    o.w = (v.w - mean) * rstd * g.w + b.w;
    ((float4*)(y + (size_t)row * D_))[threadIdx.x] = o;
}

// ---------------------------------------------------------------------------
// MFMA GEMM: C[M][N] = A[M][K] * W[N][K]^T + bias[N]  (fp32 in, bf16 MFMA)
// 128x128 tile, BK=32, 256 threads = 4 waves, each wave a 64x64 quadrant.
// ---------------------------------------------------------------------------
#define GLDS 40   // LDS row stride (bf16 elems) for 32-wide k-chunk

__global__ __launch_bounds__(256) void gemm_nt_mfma(const float* __restrict__ A,
                                                    const float* __restrict__ W,
                                                    const float* __restrict__ bias,
                                                    float* __restrict__ C,
                                                    int M, int N, int K)
{
    __shared__ bf16_t As[128 * GLDS];
    __shared__ bf16_t Bs[128 * GLDS];
    const int bm = blockIdx.y * 128, bn = blockIdx.x * 128;
    const int tid = threadIdx.x;
    const int wave = tid >> 6, lane = tid & 63;
    const int ln16 = lane & 15, quad = lane >> 4;
    const int wr = (wave >> 1) * 64;   // wave row offset in tile
    const int wc = (wave & 1) * 64;    // wave col offset in tile

    f32x4 acc[4][4];
#pragma unroll
    for (int i = 0; i < 4; i++)
#pragma unroll
        for (int j = 0; j < 4; j++) acc[i][j] = (f32x4){0.f, 0.f, 0.f, 0.f};

    for (int k0 = 0; k0 < K; k0 += 32) {
        __syncthreads();
#pragma unroll
        for (int e = tid; e < 1024; e += 256) {
            int r = e >> 3, c4 = (e & 7) << 2;
            float4 v = *(const float4*)(A + (size_t)(bm + r) * K + k0 + c4);
            bf16_t* d = &As[r * GLDS + c4];
            d[0] = (bf16_t)v.x; d[1] = (bf16_t)v.y; d[2] = (bf16_t)v.z; d[3] = (bf16_t)v.w;
        }
#pragma unroll
        for (int e = tid; e < 1024; e += 256) {
            int r = e >> 3, c4 = (e & 7) << 2;
            float4 v = *(const float4*)(W + (size_t)(bn + r) * K + k0 + c4);
            bf16_t* d = &Bs[r * GLDS + c4];
            d[0] = (bf16_t)v.x; d[1] = (bf16_t)v.y; d[2] = (bf16_t)v.z; d[3] = (bf16_t)v.w;
        }
        __syncthreads();

        bf16x8 af[4], bf[4];
#pragma unroll
        for (int mi = 0; mi < 4; mi++)
            af[mi] = *(const bf16x8*)&As[(wr + mi * 16 + ln16) * GLDS + quad * 8];
#pragma unroll
        for (int ni = 0; ni < 4; ni++)
            bf[ni] = *(const bf16x8*)&Bs[(wc + ni * 16 + ln16) * GLDS + quad * 8];
#pragma unroll
        for (int mi = 0; mi < 4; mi++)
#pragma unroll
            for (int ni = 0; ni < 4; ni++)
                acc[mi][ni] = __builtin_amdgcn_mfma_f32_16x16x32_bf16(
                    af[mi], bf[ni], acc[mi][ni], 0, 0, 0);
    }

    // epilogue: C[m][n] = acc + bias[n]; row = quad*4+r, col = ln16 (per 16x16)
#pragma unroll
    for (int ni = 0; ni < 4; ni++) {
        int n = bn + wc + ni * 16 + ln16;
        float bb = bias[n];
#pragma unroll
        for (int mi = 0; mi < 4; mi++) {
#pragma unroll
            for (int r = 0; r < 4; r++) {
                int m = bm + wr + mi * 16 + quad * 4 + r;
                C[(size_t)m * N + n] = acc[mi][ni][r] + bb;
            }
        }
    }
}

// ---------------------------------------------------------------------------
// RoPE applied in place to q and k inside the qkv buffer (fp32).
// ---------------------------------------------------------------------------
__global__ __launch_bounds__(256) void rope_kernel(float* __restrict__ qkv)
{
    int idx = blockIdx.x * blockDim.x + threadIdx.x;
    if (idx >= BS_ * H_ * 32) return;
    int i  = idx & 31;
    int h  = (idx >> 5) & 15;
    int bs = idx >> 9;
    int s  = bs & (S_ - 1);

    float inv_freq = powf(10000.0f, -(float)i / 32.0f);
    float ang = (float)s * inv_freq;
    float sn, cs;
    sincosf(ang, &sn, &cs);

    size_t base = (size_t)bs * (3 * D_) + h * (3 * HD_);
    float q1 = qkv[base + i],      q2 = qkv[base + 32 + i];
    qkv[base + i]      = q1 * cs - q2 * sn;
    qkv[base + 32 + i] = q2 * cs + q1 * sn;
    float k1 = qkv[base + 64 + i], k2 = qkv[base + 96 + i];
    qkv[base + 64 + i] = k1 * cs - k2 * sn;
    qkv[base + 96 + i] = k2 * cs + k1 * sn;
}

// ---------------------------------------------------------------------------
// MFMA flash attention, causal. Block = (q-tile 64, head, batch), 4 waves.
// Wave w owns q-rows [w*16, w*16+16). All LDS rows stride 72 bf16.
// ---------------------------------------------------------------------------
#define APAD 72

__global__ __launch_bounds__(256) void attn_mfma(const float* __restrict__ qkv,
                                                 float* __restrict__ ctx)
{
    __shared__ bf16_t Qs[64 * APAD];
    __shared__ bf16_t Ks[64 * APAD];
    __shared__ bf16_t Vt[64 * APAD];   // transposed: [hd][key]
    __shared__ bf16_t Ps[64 * APAD];   // per-wave strips, no cross-wave use

    const int qt = blockIdx.x, h = blockIdx.y, b = blockIdx.z;
    const int tid = threadIdx.x;
    const int wave = tid >> 6, lane = tid & 63;
    const int ln16 = lane & 15, quad = lane >> 4;

    const size_t rs = 3 * D_;  // qkv row stride (3072 floats)
    const float* qbase = qkv + (size_t)(b * S_ + qt * 64) * rs + h * (3 * HD_);

    // stage Q (pre-scaled by 1/8)
    for (int e = tid; e < 1024; e += 256) {
        int row = e >> 4, c4 = (e & 15) << 2;
        float4 v = *(const float4*)(qbase + (size_t)row * rs + c4);
        bf16_t* d = &Qs[row * APAD + c4];
        d[0] = (bf16_t)(v.x * 0.125f); d[1] = (bf16_t)(v.y * 0.125f);
        d[2] = (bf16_t)(v.z * 0.125f); d[3] = (bf16_t)(v.w * 0.125f);
    }

    f32x4 o[4];
#pragma unroll
    for (int nb = 0; nb < 4; nb++) o[nb] = (f32x4){0.f, 0.f, 0.f, 0.f};
    float m_i[4], l_i[4];
#pragma unroll
    for (int r = 0; r < 4; r++) { m_i[r] = -1e30f; l_i[r] = 0.f; }

    const int qg0 = qt * 64 + wave * 16 + quad * 4;   // this lane's first q row

    for (int kt = 0; kt <= qt; kt++) {
        __syncthreads();   // prev iter's reads of Ks/Vt done; Qs visible after next barrier
        const float* kbase = qkv + (size_t)(b * S_ + kt * 64) * rs + h * (3 * HD_) + HD_;
        const float* vbase = kbase + HD_;
        for (int e = tid; e < 1024; e += 256) {
            int row = e >> 4, c4 = (e & 15) << 2;
            float4 v = *(const float4*)(kbase + (size_t)row * rs + c4);
            bf16_t* d = &Ks[row * APAD + c4];
            d[0] = (bf16_t)v.x; d[1] = (bf16_t)v.y; d[2] = (bf16_t)v.z; d[3] = (bf16_t)v.w;
        }
        for (int e = tid; e < 1024; e += 256) {
            int key = e >> 4, c4 = (e & 15) << 2;   // coalesced global read
            float4 v = *(const float4*)(vbase + (size_t)key * rs + c4);
            Vt[(c4 + 0) * APAD + key] = (bf16_t)v.x;
            Vt[(c4 + 1) * APAD + key] = (bf16_t)v.y;
            Vt[(c4 + 2) * APAD + key] = (bf16_t)v.z;
            Vt[(c4 + 3) * APAD + key] = (bf16_t)v.w;
        }
        __syncthreads();

        // S = Q K^T for this wave's 16-row strip (16 x 64)
        f32x4 s[4];
#pragma unroll
        for (int cb = 0; cb < 4; cb++) s[cb] = (f32x4){0.f, 0.f, 0.f, 0.f};
#pragma unroll
        for (int kc = 0; kc < 2; kc++) {
            bf16x8 aq = *(const bf16x8*)&Qs[(wave * 16 + ln16) * APAD + kc * 32 + quad * 8];
#pragma unroll
            for (int cb = 0; cb < 4; cb++) {
                bf16x8 bk = *(const bf16x8*)&Ks[(cb * 16 + ln16) * APAD + kc * 32 + quad * 8];
                s[cb] = __builtin_amdgcn_mfma_f32_16x16x32_bf16(aq, bk, s[cb], 0, 0, 0);
            }
        }

        // causal mask on the diagonal tile
        if (kt == qt) {
#pragma unroll
            for (int cb = 0; cb < 4; cb++) {
                int key_g = kt * 64 + cb * 16 + ln16;
#pragma unroll
                for (int r = 0; r < 4; r++)
                    if (key_g > qg0 + r) s[cb][r] = -1e30f;
            }
        }

        // online softmax (per row r = quad*4+0..3; reduce across 16 lanes)
        float m_new[4], ps[4], alpha[4];
#pragma unroll
        for (int r = 0; r < 4; r++) {
            float mt = fmaxf(fmaxf(s[0][r], s[1][r]), fmaxf(s[2][r], s[3][r]));
            mt = fmaxf(mt, __shfl_xor(mt, 1));
            mt = fmaxf(mt, __shfl_xor(mt, 2));
            mt = fmaxf(mt, __shfl_xor(mt, 4));
            mt = fmaxf(mt, __shfl_xor(mt, 8));
            m_new[r] = fmaxf(m_i[r], mt);
        }
#pragma unroll
        for (int r = 0; r < 4; r++) {
            float sum = 0.f;
#pragma unroll
            for (int cb = 0; cb < 4; cb++) {
                float p = __expf(s[cb][r] - m_new[r]);
                s[cb][r] = p;
                sum += p;
            }
            sum += __shfl_xor(sum, 1);
            sum += __shfl_xor(sum, 2);
            sum += __shfl_xor(sum, 4);
            sum += __shfl_xor(sum, 8);
            ps[r] = sum;
            alpha[r] = __expf(m_i[r] - m_new[r]);
            l_i[r] = l_i[r] * alpha[r] + ps[r];
            m_i[r] = m_new[r];
        }

        // write P (bf16) to this wave's own LDS strip; rescale O
#pragma unroll
        for (int cb = 0; cb < 4; cb++)
#pragma unroll
            for (int r = 0; r < 4; r++)
                Ps[(wave * 16 + quad * 4 + r) * APAD + cb * 16 + ln16] = (bf16_t)s[cb][r];
#pragma unroll
        for (int nb = 0; nb < 4; nb++)
#pragma unroll
            for (int r = 0; r < 4; r++)
                o[nb][r] *= alpha[r];

        // O += P V   (A-frag from Ps strip, B-frag from Vt; same-wave data only)
#pragma unroll
        for (int kc = 0; kc < 2; kc++) {
            bf16x8 ap = *(const bf16x8*)&Ps[(wave * 16 + ln16) * APAD + kc * 32 + quad * 8];
#pragma unroll
            for (int nb = 0; nb < 4; nb++) {
                bf16x8 bv = *(const bf16x8*)&Vt[(nb * 16 + ln16) * APAD + kc * 32 + quad * 8];
                o[nb] = __builtin_amdgcn_mfma_f32_16x16x32_bf16(ap, bv, o[nb], 0, 0, 0);
            }
        }
    }

    // write out: ctx[b][q][h*64 + hd]
#pragma unroll
    for (int r = 0; r < 4; r++) {
        float inv_l = 1.0f / l_i[r];
        size_t row = (size_t)(b * S_ + qg0 + r - qt * 64 + qt * 64);  // = b*S + qg0 + r
        float* obase = ctx + row * D_ + h * HD_;
#pragma unroll
        for (int nb = 0; nb < 4; nb++)
            obase[nb * 16 + ln16] = o[nb][r] * inv_l;
    }
}

// ---------------------------------------------------------------------------
extern "C" void kernel_launch(void* const* d_in, const int* in_sizes, int n_in,
                              void* d_out, int out_size, void* d_ws, size_t ws_size,
                              hipStream_t stream)
{
    const float* hidden = (const float*)d_in[0];
    const float* gamma  = (const float*)d_in[1];
    const float* beta   = (const float*)d_in[2];
    const float* qkv_w  = (const float*)d_in[3];
    const float* qkv_b  = (const float*)d_in[4];
    const float* proj_w = (const float*)d_in[5];
    const float* proj_b = (const float*)d_in[6];
    float* out = (float*)d_out;

    char* ws = (char*)d_ws;
    float* x_ln = (float*)ws;                                   // 16 MB
    float* qkv  = (float*)(ws + (size_t)16 * 1024 * 1024);      // 48 MB
    float* ctx  = (float*)(ws + (size_t)64 * 1024 * 1024);      // 16 MB

    ln_kernel<<<BS_, 256, 0, stream>>>(hidden, gamma, beta, x_ln);

    gemm_nt_mfma<<<dim3((3 * D_) / 128, BS_ / 128), 256, 0, stream>>>(
        x_ln, qkv_w, qkv_b, qkv, BS_, 3 * D_, D_);

    rope_kernel<<<(BS_ * H_ * 32 + 255) / 256, 256, 0, stream>>>(qkv);

    attn_mfma<<<dim3(S_ / 64, H_, B_), 256, 0, stream>>>(qkv, ctx);

    gemm_nt_mfma<<<dim3(D_ / 128, BS_ / 128), 256, 0, stream>>>(
        ctx, proj_w, proj_b, out, BS_, D_, D_);
}

// Round 4
// 287.875 us; speedup vs baseline: 6.4249x; 1.6456x over previous
//
#include <hip/hip_runtime.h>
#include <math.h>

#define B_  2
#define S_  2048
#define D_  1024
#define H_  16
#define HD_ 64
#define BS_ (B_ * S_)   // 4096 rows

typedef __bf16 bf16_t;
typedef __bf16 bf16x8 __attribute__((ext_vector_type(8)));
typedef __bf16 bf16x4 __attribute__((ext_vector_type(4)));
typedef float  f32x4  __attribute__((ext_vector_type(4)));

#define QSCALE 0.18033688011112042f   // 0.125 * log2(e)
#define FREQC  0.28782313662425575f   // ln(10000)/32

// ---------------------------------------------------------------------------
// Weight fp32 -> bf16 convert (both weight matrices, one kernel).
// ---------------------------------------------------------------------------
__global__ __launch_bounds__(256) void cvt_w(const float* __restrict__ a,
                                             const float* __restrict__ b,
                                             bf16_t* __restrict__ oa,
                                             bf16_t* __restrict__ ob)
{
    int idx = blockIdx.x * 256 + threadIdx.x;
    const int NA = 3 * D_ * D_ / 4;   // 786432 float4 chunks in qkv_w
    if (idx < NA) {
        float4 v = ((const float4*)a)[idx];
        bf16x4 p;
        p[0] = (bf16_t)v.x; p[1] = (bf16_t)v.y; p[2] = (bf16_t)v.z; p[3] = (bf16_t)v.w;
        ((bf16x4*)oa)[idx] = p;
    } else {
        int j = idx - NA;
        float4 v = ((const float4*)b)[j];
        bf16x4 p;
        p[0] = (bf16_t)v.x; p[1] = (bf16_t)v.y; p[2] = (bf16_t)v.z; p[3] = (bf16_t)v.w;
        ((bf16x4*)ob)[j] = p;
    }
}

// ---------------------------------------------------------------------------
// LayerNorm: one block per row of 1024 floats; bf16 output.
// ---------------------------------------------------------------------------
__global__ __launch_bounds__(256) void ln_kernel(const float* __restrict__ x,
                                                 const float* __restrict__ gamma,
                                                 const float* __restrict__ beta,
                                                 bf16_t* __restrict__ y)
{
    int row = blockIdx.x;
    float4 v = ((const float4*)(x + (size_t)row * D_))[threadIdx.x];
    float sum = v.x + v.y + v.z + v.w;
    float sq  = v.x * v.x + v.y * v.y + v.z * v.z + v.w * v.w;
#pragma unroll
    for (int off = 32; off > 0; off >>= 1) {
        sum += __shfl_down(sum, off);
        sq  += __shfl_down(sq, off);
    }
    __shared__ float s_sum[4], s_sq[4];
    int wave = threadIdx.x >> 6;
    if ((threadIdx.x & 63) == 0) { s_sum[wave] = sum; s_sq[wave] = sq; }
    __syncthreads();
    float tsum = s_sum[0] + s_sum[1] + s_sum[2] + s_sum[3];
    float tsq  = s_sq[0] + s_sq[1] + s_sq[2] + s_sq[3];
    float mean = tsum * (1.0f / D_);
    float var  = tsq * (1.0f / D_) - mean * mean;
    float rstd = rsqrtf(var + 1e-5f);
    float4 g = ((const float4*)gamma)[threadIdx.x];
    float4 b = ((const float4*)beta)[threadIdx.x];
    bf16x4 o;
    o[0] = (bf16_t)((v.x - mean) * rstd * g.x + b.x);
    o[1] = (bf16_t)((v.y - mean) * rstd * g.y + b.y);
    o[2] = (bf16_t)((v.z - mean) * rstd * g.z + b.z);
    o[3] = (bf16_t)((v.w - mean) * rstd * g.w + b.w);
    *(bf16x4*)&y[(size_t)row * D_ + threadIdx.x * 4] = o;
}

// ---------------------------------------------------------------------------
// bf16 MFMA GEMM: C = A[M][K] * W[N][K]^T + bias.
// 128x128 tile, BK=32, 4 waves (64x64 quadrant each).
// MODE 0: plain fp32 output (proj). MODE 1: fused rope + scatter to
//   q[b][h][s][hd] (scaled), k[b][h][s][hd], v^T[b][h][hd][s], all bf16.
// ---------------------------------------------------------------------------
template<int MODE>
__global__ __launch_bounds__(256) void gemm_bf16(const bf16_t* __restrict__ A,
                                                 const bf16_t* __restrict__ W,
                                                 const float* __restrict__ bias,
                                                 float* __restrict__ outf,
                                                 bf16_t* __restrict__ qout,
                                                 bf16_t* __restrict__ kout,
                                                 bf16_t* __restrict__ vout,
                                                 int M, int N, int K)
{
    constexpr int SMEM = (MODE == 1) ? (4 * 64 * 72) : (2 * 128 * 40);
    __shared__ bf16_t smem[SMEM];
    bf16_t* As = smem;
    bf16_t* Bs = smem + 128 * 40;
    const int bm = blockIdx.y * 128, bn = blockIdx.x * 128;
    const int tid = threadIdx.x;
    const int wave = tid >> 6, lane = tid & 63;
    const int ln16 = lane & 15, quad = lane >> 4;
    const int wr = (wave >> 1) * 64, wc = (wave & 1) * 64;

    f32x4 acc[4][4];
#pragma unroll
    for (int i = 0; i < 4; i++)
#pragma unroll
        for (int j = 0; j < 4; j++) acc[i][j] = (f32x4){0.f, 0.f, 0.f, 0.f};

    for (int k0 = 0; k0 < K; k0 += 32) {
        __syncthreads();
#pragma unroll
        for (int i = 0; i < 2; i++) {
            int e = tid + i * 256;
            int r = e >> 2, c8 = (e & 3) << 3;
            *(bf16x8*)&As[r * 40 + c8] = *(const bf16x8*)&A[(size_t)(bm + r) * K + k0 + c8];
            *(bf16x8*)&Bs[r * 40 + c8] = *(const bf16x8*)&W[(size_t)(bn + r) * K + k0 + c8];
        }
        __syncthreads();

        bf16x8 af[4], bf[4];
#pragma unroll
        for (int mi = 0; mi < 4; mi++)
            af[mi] = *(const bf16x8*)&As[(wr + mi * 16 + ln16) * 40 + quad * 8];
#pragma unroll
        for (int ni = 0; ni < 4; ni++)
            bf[ni] = *(const bf16x8*)&Bs[(wc + ni * 16 + ln16) * 40 + quad * 8];
#pragma unroll
        for (int mi = 0; mi < 4; mi++)
#pragma unroll
            for (int ni = 0; ni < 4; ni++)
                acc[mi][ni] = __builtin_amdgcn_mfma_f32_16x16x32_bf16(
                    af[mi], bf[ni], acc[mi][ni], 0, 0, 0);
    }

    // bias (before rope: reference order)
#pragma unroll
    for (int ni = 0; ni < 4; ni++) {
        float bb = bias[bn + wc + ni * 16 + ln16];
#pragma unroll
        for (int mi = 0; mi < 4; mi++)
#pragma unroll
            for (int r = 0; r < 4; r++) acc[mi][ni][r] += bb;
    }

    if (MODE == 0) {
#pragma unroll
        for (int ni = 0; ni < 4; ni++) {
            int n = bn + wc + ni * 16 + ln16;
#pragma unroll
            for (int mi = 0; mi < 4; mi++)
#pragma unroll
                for (int r = 0; r < 4; r++)
                    outf[(size_t)(bm + wr + mi * 16 + quad * 4 + r) * N + n] = acc[mi][ni][r];
        }
    } else {
        const int n64 = (bn + wc) >> 6;   // 64-col group == one (h, t) slice
        const int t = n64 % 3, h = n64 / 3;
        __syncthreads();   // uniform: all waves done reading staging LDS
        if (t == 2) {
            // v: write transposed [b][h][hd][s]; 4 consecutive s per (mi,ni)
#pragma unroll
            for (int mi = 0; mi < 4; mi++) {
                int m0 = bm + wr + mi * 16 + quad * 4;
                int b = m0 >> 11, s0 = m0 & (S_ - 1);
#pragma unroll
                for (int ni = 0; ni < 4; ni++) {
                    int hd = ni * 16 + ln16;
                    bf16x4 pk;
#pragma unroll
                    for (int r = 0; r < 4; r++) pk[r] = (bf16_t)acc[mi][ni][r];
                    *(bf16x4*)&vout[((size_t)(b * H_ + h) * HD_ + hd) * S_ + s0] = pk;
                }
            }
        } else {
            // q/k: rope pairs are (col i, col i+32) = (acc[.][p], acc[.][p+2])
            bf16_t* T = smem + wave * (64 * 72);
            float fr0 = __expf(-(float)ln16 * FREQC);
            float fr1 = __expf(-(float)(16 + ln16) * FREQC);
            float sc = (t == 0) ? QSCALE : 1.0f;
#pragma unroll
            for (int mi = 0; mi < 4; mi++) {
#pragma unroll
                for (int r = 0; r < 4; r++) {
                    int m = bm + wr + mi * 16 + quad * 4 + r;
                    float s = (float)(m & (S_ - 1));
                    float sn0, cs0, sn1, cs1;
                    __sincosf(s * fr0, &sn0, &cs0);
                    __sincosf(s * fr1, &sn1, &cs1);
                    int rowo = (mi * 16 + quad * 4 + r) * 72;
                    float x1 = acc[mi][0][r], x2 = acc[mi][2][r];
                    T[rowo + ln16]      = (bf16_t)((x1 * cs0 - x2 * sn0) * sc);
                    T[rowo + 32 + ln16] = (bf16_t)((x2 * cs0 + x1 * sn0) * sc);
                    x1 = acc[mi][1][r]; x2 = acc[mi][3][r];
                    T[rowo + 16 + ln16] = (bf16_t)((x1 * cs1 - x2 * sn1) * sc);
                    T[rowo + 48 + ln16] = (bf16_t)((x2 * cs1 + x1 * sn1) * sc);
                }
            }
            bf16_t* dst = (t == 0) ? qout : kout;
#pragma unroll
            for (int e = lane; e < 512; e += 64) {
                int row_l = e >> 3, c8 = (e & 7) << 3;
                int m = bm + wr + row_l;
                int b = m >> 11, s = m & (S_ - 1);
                *(bf16x8*)&dst[((size_t)(b * H_ + h) * S_ + s) * HD_ + c8] =
                    *(const bf16x8*)&T[row_l * 72 + c8];
            }
        }
    }
}

// ---------------------------------------------------------------------------
// Flash attention, barrier-free. One wave = 32 q-rows of one (b,h).
// S^T = K*Q^T (q across lanes -> scalar softmax state), P^T via per-wave LDS
// strip, O^T = V^T * P^T. All MFMA fragments are contiguous loads.
// ---------------------------------------------------------------------------
__global__ __launch_bounds__(256) void attn_fa(const bf16_t* __restrict__ q_buf,
                                               const bf16_t* __restrict__ k_buf,
                                               const bf16_t* __restrict__ v_t,
                                               bf16_t* __restrict__ ctx)
{
    __shared__ bf16_t P_lds[4][32 * 72];
    const int bx = blockIdx.x, h = blockIdx.y, b = blockIdx.z;
    const int qt = (bx & 1) ? (bx >> 1) : (15 - (bx >> 1));  // pair long+short
    const int wave = threadIdx.x >> 6, lane = threadIdx.x & 63;
    const int ln16 = lane & 15, quad = lane >> 4;
    const int w0 = qt * 128 + wave * 32;

    const bf16_t* qb = q_buf + (size_t)(b * H_ + h) * S_ * HD_;
    const bf16_t* kb = k_buf + (size_t)(b * H_ + h) * S_ * HD_;
    const bf16_t* vb = v_t  + (size_t)(b * H_ + h) * HD_ * S_;
    bf16_t* Pw = &P_lds[wave][0];

    // Q B-frags, loaded once: B[k=hd][n=q] = Q[q][hd], lane n=ln16=q
    bf16x8 qf[2][2];
#pragma unroll
    for (int nq = 0; nq < 2; nq++)
#pragma unroll
        for (int kc = 0; kc < 2; kc++)
            qf[nq][kc] = *(const bf16x8*)&qb[(size_t)(w0 + nq * 16 + ln16) * HD_ + kc * 32 + quad * 8];

    f32x4 o[2][4];
#pragma unroll
    for (int nq = 0; nq < 2; nq++)
#pragma unroll
        for (int mi = 0; mi < 4; mi++) o[nq][mi] = (f32x4){0.f, 0.f, 0.f, 0.f};
    float m_i[2] = {-1e30f, -1e30f}, l_i[2] = {0.f, 0.f};
    const int kt_max = (w0 + 31) >> 6;

    for (int kt = 0; kt <= kt_max; kt++) {
        // S^T = K Q^T : A-frag = K rows (m=key), contiguous load
        f32x4 st[2][4];
#pragma unroll
        for (int nq = 0; nq < 2; nq++)
#pragma unroll
            for (int cb = 0; cb < 4; cb++) st[nq][cb] = (f32x4){0.f, 0.f, 0.f, 0.f};
#pragma unroll
        for (int kc = 0; kc < 2; kc++) {
#pragma unroll
            for (int cb = 0; cb < 4; cb++) {
                bf16x8 kf = *(const bf16x8*)&kb[(size_t)(kt * 64 + cb * 16 + ln16) * HD_ + kc * 32 + quad * 8];
                st[0][cb] = __builtin_amdgcn_mfma_f32_16x16x32_bf16(kf, qf[0][kc], st[0][cb], 0, 0, 0);
                st[1][cb] = __builtin_amdgcn_mfma_f32_16x16x32_bf16(kf, qf[1][kc], st[1][cb], 0, 0, 0);
            }
        }

        if (kt == kt_max) {   // causal mask: C-layout row=key=cb*16+quad*4+r, col=q=ln16
#pragma unroll
            for (int nq = 0; nq < 2; nq++) {
                int q_g = w0 + nq * 16 + ln16;
#pragma unroll
                for (int cb = 0; cb < 4; cb++) {
                    int key0 = kt * 64 + cb * 16 + quad * 4;
#pragma unroll
                    for (int r = 0; r < 4; r++)
                        if (key0 + r > q_g) st[nq][cb][r] = -1e30f;
                }
            }
        }

        // online softmax; scores in log2-units (q pre-scaled by log2e/8)
#pragma unroll
        for (int nq = 0; nq < 2; nq++) {
            float mx = st[nq][0][0];
#pragma unroll
            for (int cb = 0; cb < 4; cb++)
#pragma unroll
                for (int r = 0; r < 4; r++) mx = fmaxf(mx, st[nq][cb][r]);
            mx = fmaxf(mx, __shfl_xor(mx, 16));
            mx = fmaxf(mx, __shfl_xor(mx, 32));
            float mn = fmaxf(m_i[nq], mx);
            float sum = 0.f;
#pragma unroll
            for (int cb = 0; cb < 4; cb++)
#pragma unroll
                for (int r = 0; r < 4; r++) {
                    float p = exp2f(st[nq][cb][r] - mn);
                    st[nq][cb][r] = p;
                    sum += p;
                }
            sum += __shfl_xor(sum, 16);
            sum += __shfl_xor(sum, 32);
            float al = exp2f(m_i[nq] - mn);
            l_i[nq] = l_i[nq] * al + sum;
            m_i[nq] = mn;
#pragma unroll
            for (int mi = 0; mi < 4; mi++) {
                o[nq][mi][0] *= al; o[nq][mi][1] *= al;
                o[nq][mi][2] *= al; o[nq][mi][3] *= al;
            }
            // P_lds[q][key]: 4 consecutive keys per (cb) -> packed 8B write
#pragma unroll
            for (int cb = 0; cb < 4; cb++) {
                bf16x4 pk;
#pragma unroll
                for (int r = 0; r < 4; r++) pk[r] = (bf16_t)st[nq][cb][r];
                *(bf16x4*)&Pw[(nq * 16 + ln16) * 72 + cb * 16 + quad * 4] = pk;
            }
        }

        // O^T += V^T P^T : A-frag = v^T rows (m=hd), B-frag = P_lds rows (n=q)
#pragma unroll
        for (int kc = 0; kc < 2; kc++) {
            bf16x8 pf0 = *(const bf16x8*)&Pw[ln16 * 72 + kc * 32 + quad * 8];
            bf16x8 pf1 = *(const bf16x8*)&Pw[(16 + ln16) * 72 + kc * 32 + quad * 8];
#pragma unroll
            for (int mi = 0; mi < 4; mi++) {
                bf16x8 vf = *(const bf16x8*)&vb[(size_t)(mi * 16 + ln16) * S_ + kt * 64 + kc * 32 + quad * 8];
                o[0][mi] = __builtin_amdgcn_mfma_f32_16x16x32_bf16(vf, pf0, o[0][mi], 0, 0, 0);
                o[1][mi] = __builtin_amdgcn_mfma_f32_16x16x32_bf16(vf, pf1, o[1][mi], 0, 0, 0);
            }
        }
    }

    // write ctx[b][s][h*64+hd] bf16; O^T C-layout: col q=ln16, rows hd
#pragma unroll
    for (int nq = 0; nq < 2; nq++) {
        float inv = 1.0f / l_i[nq];
        int s = w0 + nq * 16 + ln16;
#pragma unroll
        for (int mi = 0; mi < 4; mi++) {
            bf16x4 pk;
#pragma unroll
            for (int r = 0; r < 4; r++) pk[r] = (bf16_t)(o[nq][mi][r] * inv);
            *(bf16x4*)&ctx[(size_t)(b * S_ + s) * D_ + h * HD_ + mi * 16 + quad * 4] = pk;
        }
    }
}

// ---------------------------------------------------------------------------
extern "C" void kernel_launch(void* const* d_in, const int* in_sizes, int n_in,
                              void* d_out, int out_size, void* d_ws, size_t ws_size,
                              hipStream_t stream)
{
    const float* hidden = (const float*)d_in[0];
    const float* gamma  = (const float*)d_in[1];
    const float* beta   = (const float*)d_in[2];
    const float* qkv_w  = (const float*)d_in[3];
    const float* qkv_b  = (const float*)d_in[4];
    const float* proj_w = (const float*)d_in[5];
    const float* proj_b = (const float*)d_in[6];
    float* out = (float*)d_out;

    char* ws = (char*)d_ws;
    const size_t MB = 1024 * 1024;
    bf16_t* x_ln = (bf16_t*)(ws);             //  0.. 8 MB
    bf16_t* wq   = (bf16_t*)(ws +  8 * MB);   //  8..14 MB
    bf16_t* wp   = (bf16_t*)(ws + 14 * MB);   // 14..16 MB
    bf16_t* qbf  = (bf16_t*)(ws + 16 * MB);   // 16..24 MB
    bf16_t* kbf  = (bf16_t*)(ws + 24 * MB);   // 24..32 MB
    bf16_t* vtb  = (bf16_t*)(ws + 32 * MB);   // 32..40 MB
    bf16_t* ctx  = (bf16_t*)(ws + 40 * MB);   // 40..48 MB

    cvt_w<<<4096, 256, 0, stream>>>(qkv_w, proj_w, wq, wp);
    ln_kernel<<<BS_, 256, 0, stream>>>(hidden, gamma, beta, x_ln);
    gemm_bf16<1><<<dim3(24, 32), 256, 0, stream>>>(
        x_ln, wq, qkv_b, nullptr, qbf, kbf, vtb, BS_, 3 * D_, D_);
    attn_fa<<<dim3(16, H_, B_), 256, 0, stream>>>(qbf, kbf, vtb, ctx);
    gemm_bf16<0><<<dim3(8, 32), 256, 0, stream>>>(
        ctx, wp, proj_b, out, nullptr, nullptr, nullptr, BS_, D_, D_);
}

// Round 5
// 236.849 us; speedup vs baseline: 7.8091x; 1.2154x over previous
//
#include <hip/hip_runtime.h>
#include <math.h>

#define B_  2
#define S_  2048
#define D_  1024
#define H_  16
#define HD_ 64
#define BS_ (B_ * S_)   // 4096 rows

typedef __bf16 bf16_t;
typedef __bf16 bf16x8 __attribute__((ext_vector_type(8)));
typedef __bf16 bf16x4 __attribute__((ext_vector_type(4)));
typedef float  f32x4  __attribute__((ext_vector_type(4)));

#define QSCALE 0.18033688011112042f   // 0.125 * log2(e)
#define FREQC  0.28782313662425575f   // ln(10000)/32

// ---------------------------------------------------------------------------
// Weight fp32 -> bf16 convert (both weight matrices, one kernel).
// ---------------------------------------------------------------------------
__global__ __launch_bounds__(256) void cvt_w(const float* __restrict__ a,
                                             const float* __restrict__ b,
                                             bf16_t* __restrict__ oa,
                                             bf16_t* __restrict__ ob)
{
    int idx = blockIdx.x * 256 + threadIdx.x;
    const int NA = 3 * D_ * D_ / 4;   // 786432 float4 chunks in qkv_w
    if (idx < NA) {
        float4 v = ((const float4*)a)[idx];
        bf16x4 p;
        p[0] = (bf16_t)v.x; p[1] = (bf16_t)v.y; p[2] = (bf16_t)v.z; p[3] = (bf16_t)v.w;
        ((bf16x4*)oa)[idx] = p;
    } else {
        int j = idx - NA;
        float4 v = ((const float4*)b)[j];
        bf16x4 p;
        p[0] = (bf16_t)v.x; p[1] = (bf16_t)v.y; p[2] = (bf16_t)v.z; p[3] = (bf16_t)v.w;
        ((bf16x4*)ob)[j] = p;
    }
}

// ---------------------------------------------------------------------------
// LayerNorm: one block per row of 1024 floats; bf16 output.
// ---------------------------------------------------------------------------
__global__ __launch_bounds__(256) void ln_kernel(const float* __restrict__ x,
                                                 const float* __restrict__ gamma,
                                                 const float* __restrict__ beta,
                                                 bf16_t* __restrict__ y)
{
    int row = blockIdx.x;
    float4 v = ((const float4*)(x + (size_t)row * D_))[threadIdx.x];
    float sum = v.x + v.y + v.z + v.w;
    float sq  = v.x * v.x + v.y * v.y + v.z * v.z + v.w * v.w;
#pragma unroll
    for (int off = 32; off > 0; off >>= 1) {
        sum += __shfl_down(sum, off);
        sq  += __shfl_down(sq, off);
    }
    __shared__ float s_sum[4], s_sq[4];
    int wave = threadIdx.x >> 6;
    if ((threadIdx.x & 63) == 0) { s_sum[wave] = sum; s_sq[wave] = sq; }
    __syncthreads();
    float tsum = s_sum[0] + s_sum[1] + s_sum[2] + s_sum[3];
    float tsq  = s_sq[0] + s_sq[1] + s_sq[2] + s_sq[3];
    float mean = tsum * (1.0f / D_);
    float var  = tsq * (1.0f / D_) - mean * mean;
    float rstd = rsqrtf(var + 1e-5f);
    float4 g = ((const float4*)gamma)[threadIdx.x];
    float4 b = ((const float4*)beta)[threadIdx.x];
    bf16x4 o;
    o[0] = (bf16_t)((v.x - mean) * rstd * g.x + b.x);
    o[1] = (bf16_t)((v.y - mean) * rstd * g.y + b.y);
    o[2] = (bf16_t)((v.z - mean) * rstd * g.z + b.z);
    o[3] = (bf16_t)((v.w - mean) * rstd * g.w + b.w);
    *(bf16x4*)&y[(size_t)row * D_ + threadIdx.x * 4] = o;
}

// ---------------------------------------------------------------------------
// bf16 MFMA GEMM: C = A[M][K] * W[N][K]^T + bias.
// 128x128 tile, BK=32, 4 waves (64x64 quadrant each).
// MODE 0: plain fp32 output (proj). MODE 1: fused rope + scatter to
//   q[b][h][s][hd] (scaled), k[b][h][s][hd], v^T[b][h][hd][s], all bf16.
// ---------------------------------------------------------------------------
template<int MODE>
__global__ __launch_bounds__(256) void gemm_bf16(const bf16_t* __restrict__ A,
                                                 const bf16_t* __restrict__ W,
                                                 const float* __restrict__ bias,
                                                 float* __restrict__ outf,
                                                 bf16_t* __restrict__ qout,
                                                 bf16_t* __restrict__ kout,
                                                 bf16_t* __restrict__ vout,
                                                 int M, int N, int K)
{
    constexpr int SMEM = (MODE == 1) ? (4 * 64 * 72) : (2 * 128 * 40);
    __shared__ bf16_t smem[SMEM];
    bf16_t* As = smem;
    bf16_t* Bs = smem + 128 * 40;
    const int bm = blockIdx.y * 128, bn = blockIdx.x * 128;
    const int tid = threadIdx.x;
    const int wave = tid >> 6, lane = tid & 63;
    const int ln16 = lane & 15, quad = lane >> 4;
    const int wr = (wave >> 1) * 64, wc = (wave & 1) * 64;

    f32x4 acc[4][4];
#pragma unroll
    for (int i = 0; i < 4; i++)
#pragma unroll
        for (int j = 0; j < 4; j++) acc[i][j] = (f32x4){0.f, 0.f, 0.f, 0.f};

    for (int k0 = 0; k0 < K; k0 += 32) {
        __syncthreads();
#pragma unroll
        for (int i = 0; i < 2; i++) {
            int e = tid + i * 256;
            int r = e >> 2, c8 = (e & 3) << 3;
            *(bf16x8*)&As[r * 40 + c8] = *(const bf16x8*)&A[(size_t)(bm + r) * K + k0 + c8];
            *(bf16x8*)&Bs[r * 40 + c8] = *(const bf16x8*)&W[(size_t)(bn + r) * K + k0 + c8];
        }
        __syncthreads();

        bf16x8 af[4], bf[4];
#pragma unroll
        for (int mi = 0; mi < 4; mi++)
            af[mi] = *(const bf16x8*)&As[(wr + mi * 16 + ln16) * 40 + quad * 8];
#pragma unroll
        for (int ni = 0; ni < 4; ni++)
            bf[ni] = *(const bf16x8*)&Bs[(wc + ni * 16 + ln16) * 40 + quad * 8];
#pragma unroll
        for (int mi = 0; mi < 4; mi++)
#pragma unroll
            for (int ni = 0; ni < 4; ni++)
                acc[mi][ni] = __builtin_amdgcn_mfma_f32_16x16x32_bf16(
                    af[mi], bf[ni], acc[mi][ni], 0, 0, 0);
    }

    // bias (before rope: reference order)
#pragma unroll
    for (int ni = 0; ni < 4; ni++) {
        float bb = bias[bn + wc + ni * 16 + ln16];
#pragma unroll
        for (int mi = 0; mi < 4; mi++)
#pragma unroll
            for (int r = 0; r < 4; r++) acc[mi][ni][r] += bb;
    }

    if (MODE == 0) {
#pragma unroll
        for (int ni = 0; ni < 4; ni++) {
            int n = bn + wc + ni * 16 + ln16;
#pragma unroll
            for (int mi = 0; mi < 4; mi++)
#pragma unroll
                for (int r = 0; r < 4; r++)
                    outf[(size_t)(bm + wr + mi * 16 + quad * 4 + r) * N + n] = acc[mi][ni][r];
        }
    } else {
        const int n64 = (bn + wc) >> 6;   // 64-col group == one (h, t) slice
        const int t = n64 % 3, h = n64 / 3;
        __syncthreads();   // uniform: all waves done reading staging LDS
        if (t == 2) {
            // v: write transposed [b][h][hd][s]; 4 consecutive s per (mi,ni)
#pragma unroll
            for (int mi = 0; mi < 4; mi++) {
                int m0 = bm + wr + mi * 16 + quad * 4;
                int b = m0 >> 11, s0 = m0 & (S_ - 1);
#pragma unroll
                for (int ni = 0; ni < 4; ni++) {
                    int hd = ni * 16 + ln16;
                    bf16x4 pk;
#pragma unroll
                    for (int r = 0; r < 4; r++) pk[r] = (bf16_t)acc[mi][ni][r];
                    *(bf16x4*)&vout[((size_t)(b * H_ + h) * HD_ + hd) * S_ + s0] = pk;
                }
            }
        } else {
            // q/k: rope pairs are (col i, col i+32) = (acc[.][p], acc[.][p+2])
            bf16_t* T = smem + wave * (64 * 72);
            float fr0 = __expf(-(float)ln16 * FREQC);
            float fr1 = __expf(-(float)(16 + ln16) * FREQC);
            float sc = (t == 0) ? QSCALE : 1.0f;
#pragma unroll
            for (int mi = 0; mi < 4; mi++) {
#pragma unroll
                for (int r = 0; r < 4; r++) {
                    int m = bm + wr + mi * 16 + quad * 4 + r;
                    float s = (float)(m & (S_ - 1));
                    float sn0, cs0, sn1, cs1;
                    __sincosf(s * fr0, &sn0, &cs0);
                    __sincosf(s * fr1, &sn1, &cs1);
                    int rowo = (mi * 16 + quad * 4 + r) * 72;
                    float x1 = acc[mi][0][r], x2 = acc[mi][2][r];
                    T[rowo + ln16]      = (bf16_t)((x1 * cs0 - x2 * sn0) * sc);
                    T[rowo + 32 + ln16] = (bf16_t)((x2 * cs0 + x1 * sn0) * sc);
                    x1 = acc[mi][1][r]; x2 = acc[mi][3][r];
                    T[rowo + 16 + ln16] = (bf16_t)((x1 * cs1 - x2 * sn1) * sc);
                    T[rowo + 48 + ln16] = (bf16_t)((x2 * cs1 + x1 * sn1) * sc);
                }
            }
            bf16_t* dst = (t == 0) ? qout : kout;
#pragma unroll
            for (int e = lane; e < 512; e += 64) {
                int row_l = e >> 3, c8 = (e & 7) << 3;
                int m = bm + wr + row_l;
                int b = m >> 11, s = m & (S_ - 1);
                *(bf16x8*)&dst[((size_t)(b * H_ + h) * S_ + s) * HD_ + c8] =
                    *(const bf16x8*)&T[row_l * 72 + c8];
            }
        }
    }
}

// ---------------------------------------------------------------------------
// Flash attention v3. Block = 64 q-rows (4 waves x 16 q), grid (32,16,2).
// K-tile (64x64) and V^T-tile (64x64) staged in LDS per block, shared by all
// waves. Register prefetch of tile kt+1 issued after the staging barrier and
// consumed at the next iteration's barrier -> global latency hidden by
// compute. P^T via per-wave LDS strip. All LDS rows stride 72 bf16.
// ---------------------------------------------------------------------------
#define AST 72

__global__ __launch_bounds__(256) void attn_fa(const bf16_t* __restrict__ q_buf,
                                               const bf16_t* __restrict__ k_buf,
                                               const bf16_t* __restrict__ v_t,
                                               bf16_t* __restrict__ ctx)
{
    __shared__ bf16_t Ks[64 * AST];
    __shared__ bf16_t Vt[64 * AST];
    __shared__ bf16_t P_lds[4 * 16 * AST];

    const int bx = blockIdx.x, h = blockIdx.y, b = blockIdx.z;
    const int qt = (bx & 1) ? (bx >> 1) : (31 - (bx >> 1));  // heavy tiles first
    const int wave = threadIdx.x >> 6, lane = threadIdx.x & 63;
    const int ln16 = lane & 15, quad = lane >> 4;
    const int w0 = qt * 64 + wave * 16;

    const bf16_t* qb = q_buf + (size_t)(b * H_ + h) * S_ * HD_;
    const bf16_t* kb = k_buf + (size_t)(b * H_ + h) * S_ * HD_;
    const bf16_t* vb = v_t  + (size_t)(b * H_ + h) * HD_ * S_;
    bf16_t* Pw = &P_lds[wave * 16 * AST];

    // staging geometry: wave w stages K rows / V^T rows [w*16, w*16+16)
    const int srow = lane >> 3;          // 0..7
    const int scol = (lane & 7) * 8;     // elem offset 0,8,..,56

    // Q B-frags (held in regs for whole kernel): B[k=hd][n=q=ln16]
    bf16x8 qf[2];
#pragma unroll
    for (int kc = 0; kc < 2; kc++)
        qf[kc] = *(const bf16x8*)&qb[(size_t)(w0 + ln16) * HD_ + kc * 32 + quad * 8];

    f32x4 o[4];
#pragma unroll
    for (int mi = 0; mi < 4; mi++) o[mi] = (f32x4){0.f, 0.f, 0.f, 0.f};
    float m_i = -1e30f, l_i = 0.f;

    // prefetch tile 0
    bf16x8 kpre[2], vpre[2];
#pragma unroll
    for (int c = 0; c < 2; c++) {
        int rl = wave * 16 + c * 8 + srow;
        kpre[c] = *(const bf16x8*)&kb[(size_t)rl * HD_ + scol];
        vpre[c] = *(const bf16x8*)&vb[(size_t)rl * S_ + scol];
    }

    for (int kt = 0; kt <= qt; kt++) {
        __syncthreads();   // all waves done reading Ks/Vt from prev iter
#pragma unroll
        for (int c = 0; c < 2; c++) {
            int rl = wave * 16 + c * 8 + srow;
            *(bf16x8*)&Ks[rl * AST + scol] = kpre[c];
            *(bf16x8*)&Vt[rl * AST + scol] = vpre[c];
        }
        __syncthreads();   // staged tile visible
        if (kt < qt) {     // prefetch next tile; drained at next iter's barrier
#pragma unroll
            for (int c = 0; c < 2; c++) {
                int rl = wave * 16 + c * 8 + srow;
                kpre[c] = *(const bf16x8*)&kb[(size_t)((kt + 1) * 64 + rl) * HD_ + scol];
                vpre[c] = *(const bf16x8*)&vb[(size_t)rl * S_ + (kt + 1) * 64 + scol];
            }
        }

        // S^T = K Q^T : 64 keys x 16 q. A-frag = K rows from LDS.
        f32x4 st[4];
#pragma unroll
        for (int cb = 0; cb < 4; cb++) st[cb] = (f32x4){0.f, 0.f, 0.f, 0.f};
#pragma unroll
        for (int kc = 0; kc < 2; kc++) {
#pragma unroll
            for (int cb = 0; cb < 4; cb++) {
                bf16x8 kf = *(const bf16x8*)&Ks[(cb * 16 + ln16) * AST + kc * 32 + quad * 8];
                st[cb] = __builtin_amdgcn_mfma_f32_16x16x32_bf16(kf, qf[kc], st[cb], 0, 0, 0);
            }
        }

        if (kt == qt) {   // causal: key row = cb*16+quad*4+r, q col = wave*16+ln16
            int qloc = wave * 16 + ln16;
#pragma unroll
            for (int cb = 0; cb < 4; cb++) {
                int key0 = cb * 16 + quad * 4;
#pragma unroll
                for (int r = 0; r < 4; r++)
                    if (key0 + r > qloc) st[cb][r] = -1e30f;
            }
        }

        // online softmax (scores in log2 units; per-lane scalar state)
        float mx = st[0][0];
#pragma unroll
        for (int cb = 0; cb < 4; cb++)
#pragma unroll
            for (int r = 0; r < 4; r++) mx = fmaxf(mx, st[cb][r]);
        mx = fmaxf(mx, __shfl_xor(mx, 16));
        mx = fmaxf(mx, __shfl_xor(mx, 32));
        float mn = fmaxf(m_i, mx);
        float sum = 0.f;
#pragma unroll
        for (int cb = 0; cb < 4; cb++)
#pragma unroll
            for (int r = 0; r < 4; r++) {
                float p = exp2f(st[cb][r] - mn);
                st[cb][r] = p;
                sum += p;
            }
        sum += __shfl_xor(sum, 16);
        sum += __shfl_xor(sum, 32);
        float al = exp2f(m_i - mn);
        l_i = l_i * al + sum;
        m_i = mn;
#pragma unroll
        for (int mi = 0; mi < 4; mi++) {
            o[mi][0] *= al; o[mi][1] *= al; o[mi][2] *= al; o[mi][3] *= al;
        }

        // P^T[q][key] -> per-wave strip (packed 8B writes)
#pragma unroll
        for (int cb = 0; cb < 4; cb++) {
            bf16x4 pk;
#pragma unroll
            for (int r = 0; r < 4; r++) pk[r] = (bf16_t)st[cb][r];
            *(bf16x4*)&Pw[ln16 * AST + cb * 16 + quad * 4] = pk;
        }

        // O^T += V^T P^T : A-frag = V^T rows (m=hd), B-frag = P strip (n=q)
#pragma unroll
        for (int kc = 0; kc < 2; kc++) {
            bf16x8 pf = *(const bf16x8*)&Pw[ln16 * AST + kc * 32 + quad * 8];
#pragma unroll
            for (int mi = 0; mi < 4; mi++) {
                bf16x8 vf = *(const bf16x8*)&Vt[(mi * 16 + ln16) * AST + kc * 32 + quad * 8];
                o[mi] = __builtin_amdgcn_mfma_f32_16x16x32_bf16(vf, pf, o[mi], 0, 0, 0);
            }
        }
    }

    // write ctx[b][s][h*64+hd] bf16; O^T C-layout: col q=ln16, rows hd
    float inv = 1.0f / l_i;
    int s = w0 + ln16;
#pragma unroll
    for (int mi = 0; mi < 4; mi++) {
        bf16x4 pk;
#pragma unroll
        for (int r = 0; r < 4; r++) pk[r] = (bf16_t)(o[mi][r] * inv);
        *(bf16x4*)&ctx[(size_t)(b * S_ + s) * D_ + h * HD_ + mi * 16 + quad * 4] = pk;
    }
}

// ---------------------------------------------------------------------------
extern "C" void kernel_launch(void* const* d_in, const int* in_sizes, int n_in,
                              void* d_out, int out_size, void* d_ws, size_t ws_size,
                              hipStream_t stream)
{
    const float* hidden = (const float*)d_in[0];
    const float* gamma  = (const float*)d_in[1];
    const float* beta   = (const float*)d_in[2];
    const float* qkv_w  = (const float*)d_in[3];
    const float* qkv_b  = (const float*)d_in[4];
    const float* proj_w = (const float*)d_in[5];
    const float* proj_b = (const float*)d_in[6];
    float* out = (float*)d_out;

    char* ws = (char*)d_ws;
    const size_t MB = 1024 * 1024;
    bf16_t* x_ln = (bf16_t*)(ws);             //  0.. 8 MB
    bf16_t* wq   = (bf16_t*)(ws +  8 * MB);   //  8..14 MB
    bf16_t* wp   = (bf16_t*)(ws + 14 * MB);   // 14..16 MB
    bf16_t* qbf  = (bf16_t*)(ws + 16 * MB);   // 16..24 MB
    bf16_t* kbf  = (bf16_t*)(ws + 24 * MB);   // 24..32 MB
    bf16_t* vtb  = (bf16_t*)(ws + 32 * MB);   // 32..40 MB
    bf16_t* ctx  = (bf16_t*)(ws + 40 * MB);   // 40..48 MB

    cvt_w<<<4096, 256, 0, stream>>>(qkv_w, proj_w, wq, wp);
    ln_kernel<<<BS_, 256, 0, stream>>>(hidden, gamma, beta, x_ln);
    gemm_bf16<1><<<dim3(24, 32), 256, 0, stream>>>(
        x_ln, wq, qkv_b, nullptr, qbf, kbf, vtb, BS_, 3 * D_, D_);
    attn_fa<<<dim3(32, H_, B_), 256, 0, stream>>>(qbf, kbf, vtb, ctx);
    gemm_bf16<0><<<dim3(8, 32), 256, 0, stream>>>(
        ctx, wp, proj_b, out, nullptr, nullptr, nullptr, BS_, D_, D_);
}

// Round 6
// 236.732 us; speedup vs baseline: 7.8130x; 1.0005x over previous
//
#include <hip/hip_runtime.h>
#include <math.h>

#define B_  2
#define S_  2048
#define D_  1024
#define H_  16
#define HD_ 64
#define BS_ (B_ * S_)   // 4096 rows

typedef __bf16 bf16_t;
typedef __bf16 bf16x8 __attribute__((ext_vector_type(8)));
typedef __bf16 bf16x4 __attribute__((ext_vector_type(4)));
typedef float  f32x4  __attribute__((ext_vector_type(4)));

#define QSCALE 0.18033688011112042f   // 0.125 * log2(e)
#define FREQC  0.28782313662425575f   // ln(10000)/32

// Async global->LDS DMA, 16 B per lane. HW semantics: LDS dest is
// wave-uniform base + lane*16, which all call sites below satisfy.
__device__ __forceinline__ void async_ld16(const bf16_t* g, bf16_t* l)
{
    __builtin_amdgcn_global_load_lds(
        (const __attribute__((address_space(1))) void*)g,
        (__attribute__((address_space(3))) void*)l,
        16, 0, 0);
}

// ---------------------------------------------------------------------------
// Weight fp32 -> bf16 convert (both weight matrices, one kernel).
// ---------------------------------------------------------------------------
__global__ __launch_bounds__(256) void cvt_w(const float* __restrict__ a,
                                             const float* __restrict__ b,
                                             bf16_t* __restrict__ oa,
                                             bf16_t* __restrict__ ob)
{
    int idx = blockIdx.x * 256 + threadIdx.x;
    const int NA = 3 * D_ * D_ / 4;   // 786432 float4 chunks in qkv_w
    if (idx < NA) {
        float4 v = ((const float4*)a)[idx];
        bf16x4 p;
        p[0] = (bf16_t)v.x; p[1] = (bf16_t)v.y; p[2] = (bf16_t)v.z; p[3] = (bf16_t)v.w;
        ((bf16x4*)oa)[idx] = p;
    } else {
        int j = idx - NA;
        float4 v = ((const float4*)b)[j];
        bf16x4 p;
        p[0] = (bf16_t)v.x; p[1] = (bf16_t)v.y; p[2] = (bf16_t)v.z; p[3] = (bf16_t)v.w;
        ((bf16x4*)ob)[j] = p;
    }
}

// ---------------------------------------------------------------------------
// LayerNorm: one block per row of 1024 floats; bf16 output.
// ---------------------------------------------------------------------------
__global__ __launch_bounds__(256) void ln_kernel(const float* __restrict__ x,
                                                 const float* __restrict__ gamma,
                                                 const float* __restrict__ beta,
                                                 bf16_t* __restrict__ y)
{
    int row = blockIdx.x;
    float4 v = ((const float4*)(x + (size_t)row * D_))[threadIdx.x];
    float sum = v.x + v.y + v.z + v.w;
    float sq  = v.x * v.x + v.y * v.y + v.z * v.z + v.w * v.w;
#pragma unroll
    for (int off = 32; off > 0; off >>= 1) {
        sum += __shfl_down(sum, off);
        sq  += __shfl_down(sq, off);
    }
    __shared__ float s_sum[4], s_sq[4];
    int wave = threadIdx.x >> 6;
    if ((threadIdx.x & 63) == 0) { s_sum[wave] = sum; s_sq[wave] = sq; }
    __syncthreads();
    float tsum = s_sum[0] + s_sum[1] + s_sum[2] + s_sum[3];
    float tsq  = s_sq[0] + s_sq[1] + s_sq[2] + s_sq[3];
    float mean = tsum * (1.0f / D_);
    float var  = tsq * (1.0f / D_) - mean * mean;
    float rstd = rsqrtf(var + 1e-5f);
    float4 g = ((const float4*)gamma)[threadIdx.x];
    float4 b = ((const float4*)beta)[threadIdx.x];
    bf16x4 o;
    o[0] = (bf16_t)((v.x - mean) * rstd * g.x + b.x);
    o[1] = (bf16_t)((v.y - mean) * rstd * g.y + b.y);
    o[2] = (bf16_t)((v.z - mean) * rstd * g.z + b.z);
    o[3] = (bf16_t)((v.w - mean) * rstd * g.w + b.w);
    *(bf16x4*)&y[(size_t)row * D_ + threadIdx.x * 4] = o;
}

// ---------------------------------------------------------------------------
// bf16 MFMA GEMM: C = A[M][K] * W[N][K]^T + bias.
// 128x128 tile, BK=32, 4 waves (64x64 quadrant each).
// Staging: global_load_lds w=16, double-buffered, ONE barrier per K-iter.
// XOR chunk swizzle: LDS slot s of row r holds global chunk s^(r&3)
// -> lane-contiguous DMA dest AND conflict-free b128 frag reads.
// MODE 0: fp32 output (proj). MODE 1: fused rope + scatter to
//   q[b][h][s][hd] (scaled), k[b][h][s][hd], v^T[b][h][hd][s], all bf16.
// ---------------------------------------------------------------------------
template<int MODE>
__global__ __launch_bounds__(256) void gemm_bf16(const bf16_t* __restrict__ A,
                                                 const bf16_t* __restrict__ W,
                                                 const float* __restrict__ bias,
                                                 float* __restrict__ outf,
                                                 bf16_t* __restrict__ qout,
                                                 bf16_t* __restrict__ kout,
                                                 bf16_t* __restrict__ vout,
                                                 int M, int N, int K)
{
    // buffers: buf d -> A at smem+d*8192, B at smem+d*8192+4096 (elems)
    constexpr int SMEM = (MODE == 1) ? 18432 : 16384;
    __shared__ bf16_t smem[SMEM];
    const int bm = blockIdx.y * 128, bn = blockIdx.x * 128;
    const int tid = threadIdx.x;
    const int wave = tid >> 6, lane = tid & 63;
    const int ln16 = lane & 15, quad = lane >> 4;
    const int wr = (wave >> 1) * 64, wc = (wave & 1) * 64;
    const int slot_a = (quad ^ (ln16 & 3)) * 8;   // frag-read chunk slot (elems)

    f32x4 acc[4][4];
#pragma unroll
    for (int i = 0; i < 4; i++)
#pragma unroll
        for (int j = 0; j < 4; j++) acc[i][j] = (f32x4){0.f, 0.f, 0.f, 0.f};

    // stage k-tile 0 into buffer 0
#pragma unroll
    for (int j = 0; j < 2; j++) {
        int e = j * 256 + tid;                    // 0..511
        int r = e >> 2, cg = ((e & 3) ^ (r & 3)) * 8;
        async_ld16(&A[(size_t)(bm + r) * K + cg], smem + e * 8);
        async_ld16(&W[(size_t)(bn + r) * K + cg], smem + 4096 + e * 8);
    }
    __syncthreads();

    for (int k0 = 0, it = 0; k0 < K; k0 += 32, it++) {
        const bf16_t* cur = smem + (it & 1) * 8192;
        bf16_t* nxt = smem + ((it & 1) ^ 1) * 8192;
        if (k0 + 32 < K) {   // DMA next tile; lands during this iter's compute
#pragma unroll
            for (int j = 0; j < 2; j++) {
                int e = j * 256 + tid;
                int r = e >> 2, cg = ((e & 3) ^ (r & 3)) * 8;
                async_ld16(&A[(size_t)(bm + r) * K + k0 + 32 + cg], nxt + e * 8);
                async_ld16(&W[(size_t)(bn + r) * K + k0 + 32 + cg], nxt + 4096 + e * 8);
            }
        }

        bf16x8 af[4], bf[4];
#pragma unroll
        for (int mi = 0; mi < 4; mi++)
            af[mi] = *(const bf16x8*)&cur[(wr + mi * 16 + ln16) * 32 + slot_a];
#pragma unroll
        for (int ni = 0; ni < 4; ni++)
            bf[ni] = *(const bf16x8*)&cur[4096 + (wc + ni * 16 + ln16) * 32 + slot_a];
#pragma unroll
        for (int mi = 0; mi < 4; mi++)
#pragma unroll
            for (int ni = 0; ni < 4; ni++)
                acc[mi][ni] = __builtin_amdgcn_mfma_f32_16x16x32_bf16(
                    af[mi], bf[ni], acc[mi][ni], 0, 0, 0);

        __syncthreads();   // publishes next tile (vmcnt drained) + read-done
    }

    // bias (before rope: reference order)
#pragma unroll
    for (int ni = 0; ni < 4; ni++) {
        float bb = bias[bn + wc + ni * 16 + ln16];
#pragma unroll
        for (int mi = 0; mi < 4; mi++)
#pragma unroll
            for (int r = 0; r < 4; r++) acc[mi][ni][r] += bb;
    }

    if (MODE == 0) {
#pragma unroll
        for (int ni = 0; ni < 4; ni++) {
            int n = bn + wc + ni * 16 + ln16;
#pragma unroll
            for (int mi = 0; mi < 4; mi++)
#pragma unroll
                for (int r = 0; r < 4; r++)
                    outf[(size_t)(bm + wr + mi * 16 + quad * 4 + r) * N + n] = acc[mi][ni][r];
        }
    } else {
        const int n64 = (bn + wc) >> 6;   // 64-col group == one (h, t) slice
        const int t = n64 % 3, h = n64 / 3;
        // loop's final barrier already passed: staging buffers reusable
        if (t == 2) {
            // v: write transposed [b][h][hd][s]; 4 consecutive s per (mi,ni)
#pragma unroll
            for (int mi = 0; mi < 4; mi++) {
                int m0 = bm + wr + mi * 16 + quad * 4;
                int b = m0 >> 11, s0 = m0 & (S_ - 1);
#pragma unroll
                for (int ni = 0; ni < 4; ni++) {
                    int hd = ni * 16 + ln16;
                    bf16x4 pk;
#pragma unroll
                    for (int r = 0; r < 4; r++) pk[r] = (bf16_t)acc[mi][ni][r];
                    *(bf16x4*)&vout[((size_t)(b * H_ + h) * HD_ + hd) * S_ + s0] = pk;
                }
            }
        } else {
            // q/k: rope pairs are (col i, col i+32) = (acc[.][p], acc[.][p+2])
            bf16_t* T = smem + wave * (64 * 72);
            float fr0 = __expf(-(float)ln16 * FREQC);
            float fr1 = __expf(-(float)(16 + ln16) * FREQC);
            float sc = (t == 0) ? QSCALE : 1.0f;
#pragma unroll
            for (int mi = 0; mi < 4; mi++) {
#pragma unroll
                for (int r = 0; r < 4; r++) {
                    int m = bm + wr + mi * 16 + quad * 4 + r;
                    float s = (float)(m & (S_ - 1));
                    float sn0, cs0, sn1, cs1;
                    __sincosf(s * fr0, &sn0, &cs0);
                    __sincosf(s * fr1, &sn1, &cs1);
                    int rowo = (mi * 16 + quad * 4 + r) * 72;
                    float x1 = acc[mi][0][r], x2 = acc[mi][2][r];
                    T[rowo + ln16]      = (bf16_t)((x1 * cs0 - x2 * sn0) * sc);
                    T[rowo + 32 + ln16] = (bf16_t)((x2 * cs0 + x1 * sn0) * sc);
                    x1 = acc[mi][1][r]; x2 = acc[mi][3][r];
                    T[rowo + 16 + ln16] = (bf16_t)((x1 * cs1 - x2 * sn1) * sc);
                    T[rowo + 48 + ln16] = (bf16_t)((x2 * cs1 + x1 * sn1) * sc);
                }
            }
            bf16_t* dst = (t == 0) ? qout : kout;
#pragma unroll
            for (int e = lane; e < 512; e += 64) {
                int row_l = e >> 3, c8 = (e & 7) << 3;
                int m = bm + wr + row_l;
                int b = m >> 11, s = m & (S_ - 1);
                *(bf16x8*)&dst[((size_t)(b * H_ + h) * S_ + s) * HD_ + c8] =
                    *(const bf16x8*)&T[row_l * 72 + c8];
            }
        }
    }
}

// ---------------------------------------------------------------------------
// Flash attention v4. Block = 64 q (4 waves x 16 q), grid (32,16,2).
// K (64x64) and V^T (64x64) tiles double-buffered in LDS via global_load_lds
// (XOR-8 chunk swizzle: LDS slot s of row r holds global chunk s^(r&7)).
// ONE barrier per kt: DMA for kt+1 issued post-barrier, lands during compute.
// ---------------------------------------------------------------------------
__global__ __launch_bounds__(256) void attn_fa(const bf16_t* __restrict__ q_buf,
                                               const bf16_t* __restrict__ k_buf,
                                               const bf16_t* __restrict__ v_t,
                                               bf16_t* __restrict__ ctx)
{
    __shared__ bf16_t KV[2][2][4096];     // [buf][K=0/V=1][64*64]
    __shared__ bf16_t P_lds[4][16 * 72];

    const int bx = blockIdx.x, h = blockIdx.y, b = blockIdx.z;
    const int qt = (bx & 1) ? (bx >> 1) : (31 - (bx >> 1));  // heavy tiles first
    const int wave = threadIdx.x >> 6, lane = threadIdx.x & 63;
    const int tid = threadIdx.x;
    const int ln16 = lane & 15, quad = lane >> 4;
    const int w0 = qt * 64 + wave * 16;
    const int s7 = ln16 & 7;   // frag-read swizzle key

    const bf16_t* qb = q_buf + (size_t)(b * H_ + h) * S_ * HD_;
    const bf16_t* kb = k_buf + (size_t)(b * H_ + h) * S_ * HD_;
    const bf16_t* vb = v_t  + (size_t)(b * H_ + h) * HD_ * S_;
    bf16_t* Pw = &P_lds[wave][0];

    // Q B-frags (regs, whole kernel): B[k=hd][n=q=ln16]
    bf16x8 qf[2];
#pragma unroll
    for (int kc = 0; kc < 2; kc++)
        qf[kc] = *(const bf16x8*)&qb[(size_t)(w0 + ln16) * HD_ + kc * 32 + quad * 8];

    f32x4 o[4];
#pragma unroll
    for (int mi = 0; mi < 4; mi++) o[mi] = (f32x4){0.f, 0.f, 0.f, 0.f};
    float m_i = -1e30f, l_i = 0.f;

    // stage tile 0 into buffer 0
#pragma unroll
    for (int j = 0; j < 2; j++) {
        int e = j * 256 + tid;                  // 0..511
        int r = e >> 3, cg = ((e & 7) ^ (r & 7)) * 8;
        async_ld16(&kb[(size_t)r * HD_ + cg], &KV[0][0][e * 8]);
        async_ld16(&vb[(size_t)r * S_ + cg],  &KV[0][1][e * 8]);
    }
    __syncthreads();

    for (int kt = 0; kt <= qt; kt++) {
        const bf16_t* Kc = &KV[kt & 1][0][0];
        const bf16_t* Vc = &KV[kt & 1][1][0];
        if (kt < qt) {   // DMA next tile into other buffer
            int kn = kt + 1;
#pragma unroll
            for (int j = 0; j < 2; j++) {
                int e = j * 256 + tid;
                int r = e >> 3, cg = ((e & 7) ^ (r & 7)) * 8;
                async_ld16(&kb[(size_t)(kn * 64 + r) * HD_ + cg], &KV[kn & 1][0][e * 8]);
                async_ld16(&vb[(size_t)r * S_ + kn * 64 + cg],    &KV[kn & 1][1][e * 8]);
            }
        }

        // S^T = K Q^T : 64 keys x 16 q. A-frag = K rows from LDS (swizzled).
        f32x4 st[4];
#pragma unroll
        for (int cb = 0; cb < 4; cb++) st[cb] = (f32x4){0.f, 0.f, 0.f, 0.f};
#pragma unroll
        for (int kc = 0; kc < 2; kc++) {
#pragma unroll
            for (int cb = 0; cb < 4; cb++) {
                bf16x8 kf = *(const bf16x8*)&Kc[(cb * 16 + ln16) * 64 + ((kc * 4 + quad) ^ s7) * 8];
                st[cb] = __builtin_amdgcn_mfma_f32_16x16x32_bf16(kf, qf[kc], st[cb], 0, 0, 0);
            }
        }

        if (kt == qt) {   // causal: key row = cb*16+quad*4+r, q col = wave*16+ln16
            int qloc = wave * 16 + ln16;
#pragma unroll
            for (int cb = 0; cb < 4; cb++) {
                int key0 = cb * 16 + quad * 4;
#pragma unroll
                for (int r = 0; r < 4; r++)
                    if (key0 + r > qloc) st[cb][r] = -1e30f;
            }
        }

        // online softmax (scores in log2 units; per-lane scalar state)
        float mx = st[0][0];
#pragma unroll
        for (int cb = 0; cb < 4; cb++)
#pragma unroll
            for (int r = 0; r < 4; r++) mx = fmaxf(mx, st[cb][r]);
        mx = fmaxf(mx, __shfl_xor(mx, 16));
        mx = fmaxf(mx, __shfl_xor(mx, 32));
        float mn = fmaxf(m_i, mx);
        float sum = 0.f;
#pragma unroll
        for (int cb = 0; cb < 4; cb++)
#pragma unroll
            for (int r = 0; r < 4; r++) {
                float p = exp2f(st[cb][r] - mn);
                st[cb][r] = p;
                sum += p;
            }
        sum += __shfl_xor(sum, 16);
        sum += __shfl_xor(sum, 32);
        float al = exp2f(m_i - mn);
        l_i = l_i * al + sum;
        m_i = mn;
#pragma unroll
        for (int mi = 0; mi < 4; mi++) {
            o[mi][0] *= al; o[mi][1] *= al; o[mi][2] *= al; o[mi][3] *= al;
        }

        // P^T[q][key] -> per-wave strip (packed 8B writes)
#pragma unroll
        for (int cb = 0; cb < 4; cb++) {
            bf16x4 pk;
#pragma unroll
            for (int r = 0; r < 4; r++) pk[r] = (bf16_t)st[cb][r];
            *(bf16x4*)&Pw[ln16 * 72 + cb * 16 + quad * 4] = pk;
        }

        // O^T += V^T P^T : A-frag = V^T rows (m=hd, swizzled), B-frag = P strip
#pragma unroll
        for (int kc = 0; kc < 2; kc++) {
            bf16x8 pf = *(const bf16x8*)&Pw[ln16 * 72 + kc * 32 + quad * 8];
#pragma unroll
            for (int mi = 0; mi < 4; mi++) {
                bf16x8 vf = *(const bf16x8*)&Vc[(mi * 16 + ln16) * 64 + ((kc * 4 + quad) ^ s7) * 8];
                o[mi] = __builtin_amdgcn_mfma_f32_16x16x32_bf16(vf, pf, o[mi], 0, 0, 0);
            }
        }

        __syncthreads();   // publishes next tile + all waves done reading cur
    }

    // write ctx[b][s][h*64+hd] bf16; O^T C-layout: col q=ln16, rows hd
    float inv = 1.0f / l_i;
    int s = w0 + ln16;
#pragma unroll
    for (int mi = 0; mi < 4; mi++) {
        bf16x4 pk;
#pragma unroll
        for (int r = 0; r < 4; r++) pk[r] = (bf16_t)(o[mi][r] * inv);
        *(bf16x4*)&ctx[(size_t)(b * S_ + s) * D_ + h * HD_ + mi * 16 + quad * 4] = pk;
    }
}

// ---------------------------------------------------------------------------
extern "C" void kernel_launch(void* const* d_in, const int* in_sizes, int n_in,
                              void* d_out, int out_size, void* d_ws, size_t ws_size,
                              hipStream_t stream)
{
    const float* hidden = (const float*)d_in[0];
    const float* gamma  = (const float*)d_in[1];
    const float* beta   = (const float*)d_in[2];
    const float* qkv_w  = (const float*)d_in[3];
    const float* qkv_b  = (const float*)d_in[4];
    const float* proj_w = (const float*)d_in[5];
    const float* proj_b = (const float*)d_in[6];
    float* out = (float*)d_out;

    char* ws = (char*)d_ws;
    const size_t MB = 1024 * 1024;
    bf16_t* x_ln = (bf16_t*)(ws);             //  0.. 8 MB
    bf16_t* wq   = (bf16_t*)(ws +  8 * MB);   //  8..14 MB
    bf16_t* wp   = (bf16_t*)(ws + 14 * MB);   // 14..16 MB
    bf16_t* qbf  = (bf16_t*)(ws + 16 * MB);   // 16..24 MB
    bf16_t* kbf  = (bf16_t*)(ws + 24 * MB);   // 24..32 MB
    bf16_t* vtb  = (bf16_t*)(ws + 32 * MB);   // 32..40 MB
    bf16_t* ctx  = (bf16_t*)(ws + 40 * MB);   // 40..48 MB

    cvt_w<<<4096, 256, 0, stream>>>(qkv_w, proj_w, wq, wp);
    ln_kernel<<<BS_, 256, 0, stream>>>(hidden, gamma, beta, x_ln);
    gemm_bf16<1><<<dim3(24, 32), 256, 0, stream>>>(
        x_ln, wq, qkv_b, nullptr, qbf, kbf, vtb, BS_, 3 * D_, D_);
    attn_fa<<<dim3(32, H_, B_), 256, 0, stream>>>(qbf, kbf, vtb, ctx);
    gemm_bf16<0><<<dim3(8, 32), 256, 0, stream>>>(
        ctx, wp, proj_b, out, nullptr, nullptr, nullptr, BS_, D_, D_);
}